// Round 1
// baseline (541.194 us; speedup 1.0000x reference)
//
#include <hip/hip_runtime.h>
#include <math.h>

#define A_N 10647
#define C_N 80
#define K_N 500
#define SORT_N 16384
#define CONF_THRF 0.3f
#define NMS_THRF 0.5f

__device__ __forceinline__ float sigmoid_ref(float x) {
    float e = expf(-x);            // ocml expf, ~1ulp
    return 1.0f / (1.0f + e);      // IEEE add + IEEE div (no fast-math)
}

__device__ __forceinline__ unsigned long long shfl_u64(unsigned long long v, int src) {
    unsigned int lo = (unsigned int)v, hi = (unsigned int)(v >> 32);
    lo = __shfl(lo, src, 64);
    hi = __shfl(hi, src, 64);
    return ((unsigned long long)hi << 32) | (unsigned long long)lo;
}

// Kernel A: per (b,a) row -> score = sigmoid(max cls)*sigmoid(conf), label = argmax
__global__ void score_kernel(const float* __restrict__ pconf,
                             const float* __restrict__ pcls,
                             float* __restrict__ scores,
                             int* __restrict__ labels,
                             int total) {
    int row = blockIdx.x * blockDim.x + threadIdx.x;
    if (row >= total) return;
    const float4* p = (const float4*)(pcls + (size_t)row * C_N);
    // single pass: max m (first occurrence index im), runner-up m2
    float m = -3.4e38f, m2 = -3.4e38f;
    int im = 0;
    for (int j = 0; j < C_N / 4; ++j) {
        float4 v = p[j];
        float vv[4] = {v.x, v.y, v.z, v.w};
        #pragma unroll
        for (int t = 0; t < 4; ++t) {
            float x = vv[t];
            if (x > m) { m2 = m; m = x; im = j * 4 + t; }
            else if (x > m2) { m2 = x; }
        }
    }
    float sbest; int ibest;
    if (m2 >= m - 1e-4f) {
        // rare: near-tie where sigmoid rounding could change argmax/max-of-sigmoid.
        // Redo exactly as ref: argmax/max over computed sigmoids, first occurrence.
        float win = m - 1e-4f;
        sbest = -1.0f; ibest = 0;
        for (int j = 0; j < C_N / 4; ++j) {
            float4 v = p[j];
            float vv[4] = {v.x, v.y, v.z, v.w};
            #pragma unroll
            for (int t = 0; t < 4; ++t) {
                if (vv[t] >= win) {
                    float s = sigmoid_ref(vv[t]);
                    if (s > sbest) { sbest = s; ibest = j * 4 + t; }
                }
            }
        }
    } else {
        sbest = sigmoid_ref(m);
        ibest = im;
    }
    float sc = sigmoid_ref(pconf[row]);
    scores[row] = __fmul_rn(sbest, sc);   // ref: cls_conf * conf
    labels[row] = ibest;
}

// Kernel B: one block per batch. Bitonic full sort (desc) of packed keys,
// decode top-500, parallel suppression matrix, sequential keep-scan.
__global__ __launch_bounds__(1024) void topk_nms_kernel(
    const float* __restrict__ scores,
    const int* __restrict__ labels,
    const float* __restrict__ ptxywh,
    const float* __restrict__ grid_xy,
    const float* __restrict__ anchor_wh,
    const float* __restrict__ fsize,
    float* __restrict__ out, int B) {
    extern __shared__ unsigned char smem[];
    unsigned long long* keys = (unsigned long long*)smem;   // 16384*8 = 128 KiB
    const int b = blockIdx.x;
    const int tid = threadIdx.x;
    const float* sb = scores + (size_t)b * A_N;

    // load + pad
    for (int i = tid; i < SORT_N; i += 1024) {
        unsigned long long k = 0ull;
        if (i < A_N) {
            unsigned int sbits = __float_as_uint(sb[i]);  // scores in (0,1): monotone bits
            k = ((unsigned long long)sbits << 32) | (unsigned long long)(0xFFFFu - (unsigned)i);
        }
        keys[i] = k;
    }
    __syncthreads();

    // bitonic sort, final order descending (ties -> lower original index first)
    for (int sz = 2; sz <= SORT_N; sz <<= 1) {
        for (int j = sz >> 1; j > 0; j >>= 1) {
            for (int i = tid; i < SORT_N; i += 1024) {
                int l = i ^ j;
                if (l > i) {
                    unsigned long long a = keys[i];
                    unsigned long long c = keys[l];
                    bool descBlk = ((i & sz) == 0);
                    bool dosw = descBlk ? (a < c) : (a > c);
                    if (dosw) { keys[i] = c; keys[l] = a; }
                }
            }
            __syncthreads();
        }
    }

    unsigned long long myk = 0ull;
    if (tid < K_N) myk = keys[tid];
    __syncthreads();   // smem reusable now

    // LDS layout (bytes)
    float* bxL   = (float*)smem;                               // [500*4]
    float* areaL = (float*)(smem + 8000);                      // [500]
    int*   labL  = (int*)  (smem + 10000);                     // [500]
    float* valsL = (float*)(smem + 12000);                     // [500]
    unsigned long long* nzL   = (unsigned long long*)(smem + 14016); // [8]
    unsigned long long* keepL = (unsigned long long*)(smem + 14080); // [8]
    unsigned long long* supL  = (unsigned long long*)(smem + 14336); // [500*8]

    if (tid >= 512 && tid < 520) nzL[tid - 512] = 0ull;

    const size_t BK = (size_t)B * K_N;
    if (tid < K_N) {
        float scv = __uint_as_float((unsigned int)(myk >> 32));
        int idx = 0xFFFF - (int)(myk & 0xFFFFull);
        int lb = labels[(size_t)b * A_N + idx] + 1;
        const float* t4 = ptxywh + ((size_t)b * A_N + idx) * 4;
        float tx = t4[0], ty = t4[1], tw = t4[2], th = t4[3];
        float gx = grid_xy[idx * 2 + 0], gy = grid_xy[idx * 2 + 1];
        float aw = anchor_wh[idx * 2 + 0], ah = anchor_wh[idx * 2 + 1];
        float fs = fsize[idx];
        float cx = __fdiv_rn(__fadd_rn(sigmoid_ref(tx), gx), fs);
        float cy = __fdiv_rn(__fadd_rn(sigmoid_ref(ty), gy), fs);
        float wx = __fmul_rn(expf(tw), aw);
        float wy = __fmul_rn(expf(th), ah);
        float hx = __fmul_rn(0.5f, wx);
        float hy = __fmul_rn(0.5f, wy);
        float x0 = __fsub_rn(cx, hx), y0 = __fsub_rn(cy, hy);
        float x1 = __fadd_rn(cx, hx), y1 = __fadd_rn(cy, hy);
        x0 = fminf(fmaxf(x0, 0.0f), 1.0f);
        y0 = fminf(fmaxf(y0, 0.0f), 1.0f);
        x1 = fminf(fmaxf(x1, 0.0f), 1.0f);
        y1 = fminf(fmaxf(y1, 0.0f), 1.0f);
        float area = __fmul_rn(fmaxf(__fsub_rn(x1, x0), 0.0f),
                               fmaxf(__fsub_rn(y1, y0), 0.0f));
        bxL[tid * 4 + 0] = x0; bxL[tid * 4 + 1] = y0;
        bxL[tid * 4 + 2] = x1; bxL[tid * 4 + 3] = y1;
        areaL[tid] = area; labL[tid] = lb; valsL[tid] = scv;

        out[(size_t)b * K_N + tid] = (float)b;                         // ids_batch
        float* ob = out + BK + ((size_t)b * K_N + tid) * 4;            // boxes
        ob[0] = x0; ob[1] = y0; ob[2] = x1; ob[3] = y1;
        out[5 * BK + (size_t)b * K_N + tid] = (float)lb;               // labels
        out[6 * BK + (size_t)b * K_N + tid] = scv;                     // vals
    }
    __syncthreads();

    // suppression matrix: sup[i][j] for j>i, 500 rows x 8 u64 words
    for (int task = tid; task < K_N * 8; task += 1024) {
        int i = task >> 3;
        int w = task & 7;
        float li = bxL[i * 4 + 0], ti = bxL[i * 4 + 1];
        float ri = bxL[i * 4 + 2], bi = bxL[i * 4 + 3];
        float ai = areaL[i];
        int lbi = labL[i];
        unsigned long long bits = 0ull;
        int j0 = w * 64;
        int jend = j0 + 64; if (jend > K_N) jend = K_N;
        int jst = j0 > i + 1 ? j0 : i + 1;
        for (int j = jst; j < jend; ++j) {
            if (labL[j] == lbi) {
                float lj = bxL[j * 4 + 0], tj = bxL[j * 4 + 1];
                float rj = bxL[j * 4 + 2], bj = bxL[j * 4 + 3];
                float ltx = fmaxf(li, lj), lty = fmaxf(ti, tj);
                float rbx = fminf(ri, rj), rby = fminf(bi, bj);
                float iw = fmaxf(__fsub_rn(rbx, ltx), 0.0f);
                float ih = fmaxf(__fsub_rn(rby, lty), 0.0f);
                float inter = __fmul_rn(iw, ih);
                float den = __fadd_rn(__fsub_rn(__fadd_rn(ai, areaL[j]), inter), 1e-9f);
                float iou = __fdiv_rn(inter, den);
                if (iou > NMS_THRF) bits |= (1ull << (j - j0));
            }
        }
        supL[i * 8 + w] = bits;
        if (bits) atomicOr(&nzL[i >> 6], 1ull << (i & 63));
    }
    __syncthreads();

    // sequential keep-scan, wave 0, register-resident suppressed bitmask
    if (tid < 64) {
        const int lane = tid;
        unsigned long long supp = 0ull, keepm = 0ull;
        unsigned long long nzreg = (lane < 8) ? nzL[lane] : 0ull;
        #pragma unroll
        for (int t = 0; t < 8; ++t) {
            const int i0 = t * 64;
            int myi = i0 + lane;
            bool v = (myi < K_N) ? (valsL[myi] > CONF_THRF) : false;
            unsigned long long vword = __ballot(v);
            unsigned long long nzword = shfl_u64(nzreg, t);
            const int imax = (K_N - i0 < 64) ? (K_N - i0) : 64;
            for (int i2 = 0; i2 < imax; ++i2) {
                unsigned long long sw = shfl_u64(supp, t);
                bool keep_i = ((vword >> i2) & 1ull) && !((sw >> i2) & 1ull);
                if (keep_i) {
                    if (lane == t) keepm |= (1ull << i2);
                    if ((nzword >> i2) & 1ull) {
                        if (lane < 8) supp |= supL[(i0 + i2) * 8 + lane];
                    }
                }
            }
        }
        if (lane < 8) keepL[lane] = keepm;
    }
    __syncthreads();

    if (tid < K_N) {
        unsigned long long kw = keepL[tid >> 6];
        out[7 * BK + (size_t)b * K_N + tid] = (float)((kw >> (tid & 63)) & 1ull);
    }
}

extern "C" void kernel_launch(void* const* d_in, const int* in_sizes, int n_in,
                              void* d_out, int out_size, void* d_ws, size_t ws_size,
                              hipStream_t stream) {
    const float* pconf     = (const float*)d_in[0];
    const float* pcls      = (const float*)d_in[1];
    const float* ptxywh    = (const float*)d_in[2];
    const float* grid_xy   = (const float*)d_in[3];
    const float* anchor_wh = (const float*)d_in[4];
    const float* fsize     = (const float*)d_in[5];
    int total = in_sizes[0];          // B*A
    int B = total / A_N;
    if (B <= 0) return;

    float* scores = (float*)d_ws;
    int*   labls  = (int*)((char*)d_ws + (size_t)total * sizeof(float));
    float* out    = (float*)d_out;

    int blocks = (total + 255) / 256;
    hipLaunchKernelGGL(score_kernel, dim3(blocks), dim3(256), 0, stream,
                       pconf, pcls, scores, labls, total);
    hipLaunchKernelGGL(topk_nms_kernel, dim3(B), dim3(1024), 131072, stream,
                       scores, labls, ptxywh, grid_xy, anchor_wh, fsize, out, B);
}

// Round 2
// 206.276 us; speedup vs baseline: 2.6236x; 2.6236x over previous
//
#include <hip/hip_runtime.h>
#include <math.h>

#define A_N 10647
#define C_N 80
#define K_N 500
#define CONF_THRF 0.3f
#define NMS_THRF 0.5f

#define ROWS_TILE 256
#define PADF 84                 // 80 floats padded to 84 -> conflict-free b128 reads
#define NTILES ((A_N + ROWS_TILE - 1) / ROWS_TILE)   // 42

#define NBUCK 1024              // scores in (0,1): bits>>20 < 1016
#define CAND_N 2048

__device__ __forceinline__ float sigmoid_ref(float x) {
    float e = expf(-x);            // ocml expf, ~1ulp
    return 1.0f / (1.0f + e);      // IEEE add + IEEE div (no fast-math)
}

__device__ __forceinline__ unsigned long long shfl_u64(unsigned long long v, int src) {
    unsigned int lo = (unsigned int)v, hi = (unsigned int)(v >> 32);
    lo = __shfl(lo, src, 64);
    hi = __shfl(hi, src, 64);
    return ((unsigned long long)hi << 32) | (unsigned long long)lo;
}

// Kernel A: LDS-staged streaming score pass.
// Block = 256 threads, one (batch, 256-row tile). Coalesced global float4 loads
// -> padded LDS rows -> per-thread row reduction.
__global__ __launch_bounds__(256) void score_kernel(
    const float* __restrict__ pconf,
    const float* __restrict__ pcls,
    float* __restrict__ scores,
    int* __restrict__ labels) {
    extern __shared__ float lds[];          // ROWS_TILE * PADF floats = 86016 B
    const int b = blockIdx.x / NTILES;
    const int tile = blockIdx.x % NTILES;
    const int row0 = tile * ROWS_TILE;
    int nrows = A_N - row0; if (nrows > ROWS_TILE) nrows = ROWS_TILE;
    const int tid = threadIdx.x;

    const float4* src = (const float4*)(pcls + ((size_t)b * A_N + row0) * C_N);
    const int nf4 = nrows * (C_N / 4);
    for (int t = tid; t < nf4; t += ROWS_TILE) {
        float4 v = src[t];
        int r = t / (C_N / 4);
        int c = t - r * (C_N / 4);
        *(float4*)(lds + r * PADF + c * 4) = v;   // 336B row stride, 16B aligned
    }
    __syncthreads();

    if (tid < nrows) {
        const float* rowp = lds + tid * PADF;
        // pass 1: max (branchless tree)
        float m = -3.4e38f;
        #pragma unroll
        for (int j = 0; j < C_N / 4; ++j) {
            float4 v = *(const float4*)(rowp + j * 4);
            m = fmaxf(m, fmaxf(fmaxf(v.x, v.y), fmaxf(v.z, v.w)));
        }
        // pass 2: first index of max + count of near-ties (backward overwrite)
        float win = m - 1e-4f;
        int im = 0, cnt = 0;
        #pragma unroll
        for (int j = C_N / 4 - 1; j >= 0; --j) {
            float4 v = *(const float4*)(rowp + j * 4);
            if (v.w == m) im = j * 4 + 3;  cnt += (v.w >= win);
            if (v.z == m) im = j * 4 + 2;  cnt += (v.z >= win);
            if (v.y == m) im = j * 4 + 1;  cnt += (v.y >= win);
            if (v.x == m) im = j * 4 + 0;  cnt += (v.x >= win);
        }
        float sbest; int ibest;
        if (cnt >= 2) {
            // rare: a second raw value within 1e-4 of max -> sigmoid rounding could
            // change argmax/max-of-sigmoid. Redo exactly as ref (first occurrence).
            sbest = -1.0f; ibest = 0;
            for (int i = 0; i < C_N; ++i) {
                float x = rowp[i];
                if (x >= win) {
                    float s = sigmoid_ref(x);
                    if (s > sbest) { sbest = s; ibest = i; }
                }
            }
        } else {
            sbest = sigmoid_ref(m);
            ibest = im;
        }
        size_t grow = (size_t)b * A_N + row0 + tid;
        float cf = sigmoid_ref(pconf[grow]);
        scores[grow] = __fmul_rn(sbest, cf);   // ref: cls_conf * conf
        labels[grow] = ibest;
    }
}

// Kernel B: one block per batch. Histogram select -> 2048-key bitonic sort ->
// decode top-500 -> suppression matrix -> sequential keep-scan.
__global__ __launch_bounds__(1024) void topk_nms_kernel(
    const float* __restrict__ scores,
    const int* __restrict__ labels,
    const float* __restrict__ ptxywh,
    const float* __restrict__ grid_xy,
    const float* __restrict__ anchor_wh,
    const float* __restrict__ fsize,
    float* __restrict__ out, int B) {
    extern __shared__ unsigned char smem[];
    // phase 1 layout
    unsigned int* hist = (unsigned int*)smem;                     // [1024]  @0
    unsigned long long* cand = (unsigned long long*)(smem + 4096);// [2048]  @4096..20480
    unsigned int* cntp = (unsigned int*)(smem + 20480);
    unsigned int* Tp   = (unsigned int*)(smem + 20484);
    const int b = blockIdx.x;
    const int tid = threadIdx.x;
    const float* sb = scores + (size_t)b * A_N;

    // init
    hist[tid] = 0u;
    cand[tid] = 0ull;
    cand[tid + 1024] = 0ull;
    if (tid == 0) *cntp = 0u;
    __syncthreads();

    // histogram of top-12 float bits (all scores positive, < 1.0)
    for (int i = tid; i < A_N; i += 1024) {
        unsigned int u = __float_as_uint(sb[i]) >> 20;
        atomicAdd(&hist[u], 1u);
    }
    __syncthreads();

    // suffix scan (Hillis-Steele): hist[u] = count of items in buckets >= u
    for (int d = 1; d < NBUCK; d <<= 1) {
        unsigned int v = (tid + d < NBUCK) ? hist[tid + d] : 0u;
        __syncthreads();
        hist[tid] += v;
        __syncthreads();
    }
    // T = max u with cum[u] >= K_N  (cum[0] = A_N >= K_N always)
    if (hist[tid] >= K_N && (tid == NBUCK - 1 || hist[tid + 1] < K_N)) *Tp = (unsigned)tid;
    __syncthreads();
    const unsigned int T = *Tp;
    __syncthreads();

    // gather candidates (buckets >= T); expected ~800, cap CAND_N
    for (int i = tid; i < A_N; i += 1024) {
        unsigned int u = __float_as_uint(sb[i]);
        if ((u >> 20) >= T) {
            unsigned int slot = atomicAdd(cntp, 1u);
            if (slot < CAND_N)
                cand[slot] = ((unsigned long long)u << 32) |
                             (unsigned long long)(0xFFFFu - (unsigned)i);
        }
    }
    __syncthreads();

    // bitonic sort 2048 desc (1024 threads -> exactly one pair each)
    for (int sz = 2; sz <= CAND_N; sz <<= 1) {
        for (int j = sz >> 1; j > 0; j >>= 1) {
            int i = ((tid & ~(j - 1)) << 1) | (tid & (j - 1));
            int l = i | j;
            unsigned long long a = cand[i];
            unsigned long long c = cand[l];
            bool descBlk = ((i & sz) == 0);
            if (descBlk ? (a < c) : (a > c)) { cand[i] = c; cand[l] = a; }
            __syncthreads();
        }
    }

    unsigned long long myk = 0ull;
    if (tid < K_N) myk = cand[tid];
    __syncthreads();   // smem reusable now

    // phase 2 layout (bytes)
    float* bxL   = (float*)smem;                               // [500*4]
    float* areaL = (float*)(smem + 8000);                      // [500]
    int*   labL  = (int*)  (smem + 10000);                     // [500]
    float* valsL = (float*)(smem + 12000);                     // [500]
    unsigned long long* nzL   = (unsigned long long*)(smem + 14016); // [8]
    unsigned long long* keepL = (unsigned long long*)(smem + 14080); // [8]
    unsigned long long* supL  = (unsigned long long*)(smem + 14336); // [500*8]

    if (tid >= 512 && tid < 520) nzL[tid - 512] = 0ull;

    const size_t BK = (size_t)B * K_N;
    if (tid < K_N) {
        float scv = __uint_as_float((unsigned int)(myk >> 32));
        int idx = 0xFFFF - (int)(myk & 0xFFFFull);
        int lb = labels[(size_t)b * A_N + idx] + 1;
        const float* t4 = ptxywh + ((size_t)b * A_N + idx) * 4;
        float tx = t4[0], ty = t4[1], tw = t4[2], th = t4[3];
        float gx = grid_xy[idx * 2 + 0], gy = grid_xy[idx * 2 + 1];
        float aw = anchor_wh[idx * 2 + 0], ah = anchor_wh[idx * 2 + 1];
        float fs = fsize[idx];
        float cx = __fdiv_rn(__fadd_rn(sigmoid_ref(tx), gx), fs);
        float cy = __fdiv_rn(__fadd_rn(sigmoid_ref(ty), gy), fs);
        float wx = __fmul_rn(expf(tw), aw);
        float wy = __fmul_rn(expf(th), ah);
        float hx = __fmul_rn(0.5f, wx);
        float hy = __fmul_rn(0.5f, wy);
        float x0 = __fsub_rn(cx, hx), y0 = __fsub_rn(cy, hy);
        float x1 = __fadd_rn(cx, hx), y1 = __fadd_rn(cy, hy);
        x0 = fminf(fmaxf(x0, 0.0f), 1.0f);
        y0 = fminf(fmaxf(y0, 0.0f), 1.0f);
        x1 = fminf(fmaxf(x1, 0.0f), 1.0f);
        y1 = fminf(fmaxf(y1, 0.0f), 1.0f);
        float area = __fmul_rn(fmaxf(__fsub_rn(x1, x0), 0.0f),
                               fmaxf(__fsub_rn(y1, y0), 0.0f));
        bxL[tid * 4 + 0] = x0; bxL[tid * 4 + 1] = y0;
        bxL[tid * 4 + 2] = x1; bxL[tid * 4 + 3] = y1;
        areaL[tid] = area; labL[tid] = lb; valsL[tid] = scv;

        out[(size_t)b * K_N + tid] = (float)b;                         // ids_batch
        float* ob = out + BK + ((size_t)b * K_N + tid) * 4;            // boxes
        ob[0] = x0; ob[1] = y0; ob[2] = x1; ob[3] = y1;
        out[5 * BK + (size_t)b * K_N + tid] = (float)lb;               // labels
        out[6 * BK + (size_t)b * K_N + tid] = scv;                     // vals
    }
    __syncthreads();

    // suppression matrix: sup[i][j] for j>i, 500 rows x 8 u64 words
    for (int task = tid; task < K_N * 8; task += 1024) {
        int i = task >> 3;
        int w = task & 7;
        float li = bxL[i * 4 + 0], ti = bxL[i * 4 + 1];
        float ri = bxL[i * 4 + 2], bi = bxL[i * 4 + 3];
        float ai = areaL[i];
        int lbi = labL[i];
        unsigned long long bits = 0ull;
        int j0 = w * 64;
        int jend = j0 + 64; if (jend > K_N) jend = K_N;
        int jst = j0 > i + 1 ? j0 : i + 1;
        for (int j = jst; j < jend; ++j) {
            if (labL[j] == lbi) {
                float lj = bxL[j * 4 + 0], tj = bxL[j * 4 + 1];
                float rj = bxL[j * 4 + 2], bj = bxL[j * 4 + 3];
                float ltx = fmaxf(li, lj), lty = fmaxf(ti, tj);
                float rbx = fminf(ri, rj), rby = fminf(bi, bj);
                float iw = fmaxf(__fsub_rn(rbx, ltx), 0.0f);
                float ih = fmaxf(__fsub_rn(rby, lty), 0.0f);
                float inter = __fmul_rn(iw, ih);
                float den = __fadd_rn(__fsub_rn(__fadd_rn(ai, areaL[j]), inter), 1e-9f);
                float iou = __fdiv_rn(inter, den);
                if (iou > NMS_THRF) bits |= (1ull << (j - j0));
            }
        }
        supL[i * 8 + w] = bits;
        if (bits) atomicOr(&nzL[i >> 6], 1ull << (i & 63));
    }
    __syncthreads();

    // sequential keep-scan, wave 0, register-resident suppressed bitmask
    if (tid < 64) {
        const int lane = tid;
        unsigned long long supp = 0ull, keepm = 0ull;
        unsigned long long nzreg = (lane < 8) ? nzL[lane] : 0ull;
        #pragma unroll
        for (int t = 0; t < 8; ++t) {
            const int i0 = t * 64;
            int myi = i0 + lane;
            bool v = (myi < K_N) ? (valsL[myi] > CONF_THRF) : false;
            unsigned long long vword = __ballot(v);
            unsigned long long nzword = shfl_u64(nzreg, t);
            const int imax = (K_N - i0 < 64) ? (K_N - i0) : 64;
            for (int i2 = 0; i2 < imax; ++i2) {
                unsigned long long sw = shfl_u64(supp, t);
                bool keep_i = ((vword >> i2) & 1ull) && !((sw >> i2) & 1ull);
                if (keep_i) {
                    if (lane == t) keepm |= (1ull << i2);
                    if ((nzword >> i2) & 1ull) {
                        if (lane < 8) supp |= supL[(i0 + i2) * 8 + lane];
                    }
                }
            }
        }
        if (lane < 8) keepL[lane] = keepm;
    }
    __syncthreads();

    if (tid < K_N) {
        unsigned long long kw = keepL[tid >> 6];
        out[7 * BK + (size_t)b * K_N + tid] = (float)((kw >> (tid & 63)) & 1ull);
    }
}

extern "C" void kernel_launch(void* const* d_in, const int* in_sizes, int n_in,
                              void* d_out, int out_size, void* d_ws, size_t ws_size,
                              hipStream_t stream) {
    const float* pconf     = (const float*)d_in[0];
    const float* pcls      = (const float*)d_in[1];
    const float* ptxywh    = (const float*)d_in[2];
    const float* grid_xy   = (const float*)d_in[3];
    const float* anchor_wh = (const float*)d_in[4];
    const float* fsize     = (const float*)d_in[5];
    int total = in_sizes[0];          // B*A
    int B = total / A_N;
    if (B <= 0) return;

    float* scores = (float*)d_ws;
    int*   labls  = (int*)((char*)d_ws + (size_t)total * sizeof(float));
    float* out    = (float*)d_out;

    hipLaunchKernelGGL(score_kernel, dim3(B * NTILES), dim3(ROWS_TILE),
                       ROWS_TILE * PADF * sizeof(float), stream,
                       pconf, pcls, scores, labls);
    hipLaunchKernelGGL(topk_nms_kernel, dim3(B), dim3(1024), 46592, stream,
                       scores, labls, ptxywh, grid_xy, anchor_wh, fsize, out, B);
}

// Round 3
// 143.126 us; speedup vs baseline: 3.7812x; 1.4412x over previous
//
#include <hip/hip_runtime.h>
#include <math.h>

#define A_N 10647
#define C_N 80
#define K_N 500
#define CONF_THRF 0.3f
#define NMS_THRF 0.5f

#define NBUCK 1024              // scores in (0,1): bits>>20 < 1016
#define CAND_N 2048

#define ROWS_PER_BLOCK 64
#define SC_TILES ((A_N + ROWS_PER_BLOCK - 1) / ROWS_PER_BLOCK)   // 167

__device__ __forceinline__ float sigmoid_ref(float x) {
    float e = expf(-x);            // ocml expf, ~1ulp
    return 1.0f / (1.0f + e);      // IEEE add + IEEE div (no fast-math)
}

__device__ __forceinline__ unsigned long long shfl_u64(unsigned long long v, int src) {
    unsigned int lo = (unsigned int)v, hi = (unsigned int)(v >> 32);
    lo = __shfl(lo, src, 64);
    hi = __shfl(hi, src, 64);
    return ((unsigned long long)hi << 32) | (unsigned long long)lo;
}

__device__ __forceinline__ unsigned long long shfl_xor_u64(unsigned long long v, int mask) {
    unsigned int lo = (unsigned int)v, hi = (unsigned int)(v >> 32);
    lo = __shfl_xor(lo, mask, 64);
    hi = __shfl_xor(hi, mask, 64);
    return ((unsigned long long)hi << 32) | (unsigned long long)lo;
}

// Kernel A: 4 lanes per row, no LDS. Wave = 16 rows, block(256) = 64 rows.
// Lane (sub = lane&3) reads float4 #{sub, sub+4, ..., sub+16} of its row:
// each wave-instruction touches 16 aligned 64B lines -> fully coalesced.
__global__ __launch_bounds__(256) void score_kernel(
    const float* __restrict__ pconf,
    const float* __restrict__ pcls,
    float* __restrict__ scores,
    int* __restrict__ labels) {
    const int tid  = threadIdx.x;
    const int lane = tid & 63;
    const int wave = tid >> 6;
    const int sub  = lane & 3;
    const int b    = blockIdx.x / SC_TILES;
    const int tile = blockIdx.x % SC_TILES;
    const int row  = tile * ROWS_PER_BLOCK + wave * 16 + (lane >> 2);
    const bool valid = row < A_N;
    const size_t grow = (size_t)b * A_N + row;

    float4 v[5];
    if (valid) {
        const float4* rp = (const float4*)(pcls + grow * C_N);
        #pragma unroll
        for (int j = 0; j < 5; ++j) v[j] = rp[sub + 4 * j];
    } else {
        #pragma unroll
        for (int j = 0; j < 5; ++j)
            v[j] = make_float4(-3.4e38f, -3.4e38f, -3.4e38f, -3.4e38f);
    }

    // group max (exact)
    float m = -3.4e38f;
    #pragma unroll
    for (int j = 0; j < 5; ++j)
        m = fmaxf(m, fmaxf(fmaxf(v[j].x, v[j].y), fmaxf(v[j].z, v[j].w)));
    m = fmaxf(m, __shfl_xor(m, 1, 64));
    m = fmaxf(m, __shfl_xor(m, 2, 64));

    // first index of max + count of near-ties
    const float win = m - 1e-4f;
    int imin = 0x7FFFFFFF, cnt = 0;
    #pragma unroll
    for (int j = 0; j < 5; ++j) {
        float arr[4] = {v[j].x, v[j].y, v[j].z, v[j].w};
        #pragma unroll
        for (int t = 0; t < 4; ++t) {
            int idx = (sub + 4 * j) * 4 + t;
            if (arr[t] == m && idx < imin) imin = idx;
            cnt += (arr[t] >= win) ? 1 : 0;
        }
    }
    {
        int o = __shfl_xor(imin, 1, 64); imin = imin < o ? imin : o;
        o = __shfl_xor(imin, 2, 64);     imin = imin < o ? imin : o;
        cnt += __shfl_xor(cnt, 1, 64);
        cnt += __shfl_xor(cnt, 2, 64);
    }

    float sbest; int ibest;
    if (cnt >= 2) {
        // rare: a second raw value within 1e-4 of max -> sigmoid rounding could
        // change argmax/max-of-sigmoid. Redo exactly as ref: max sigmoid,
        // first-occurrence tie-break (key = s_bits desc, then idx asc).
        unsigned long long key = 0ull;
        #pragma unroll
        for (int j = 0; j < 5; ++j) {
            float arr[4] = {v[j].x, v[j].y, v[j].z, v[j].w};
            #pragma unroll
            for (int t = 0; t < 4; ++t) {
                float x = arr[t];
                if (x >= win) {
                    int idx = (sub + 4 * j) * 4 + t;
                    float s = sigmoid_ref(x);
                    unsigned long long k =
                        ((unsigned long long)__float_as_uint(s) << 32) |
                        (unsigned long long)(0xFFFFu - (unsigned)idx);
                    if (k > key) key = k;
                }
            }
        }
        unsigned long long o = shfl_xor_u64(key, 1); if (o > key) key = o;
        o = shfl_xor_u64(key, 2);                    if (o > key) key = o;
        sbest = __uint_as_float((unsigned int)(key >> 32));
        ibest = 0xFFFF - (int)(key & 0xFFFFull);
    } else {
        sbest = sigmoid_ref(m);
        ibest = imin;
    }

    if (sub == 0 && valid) {
        float cf = sigmoid_ref(pconf[grow]);
        scores[grow] = __fmul_rn(sbest, cf);   // ref: cls_conf * conf
        labels[grow] = ibest;
    }
}

// Kernel B: one block per batch. Histogram select -> 2048-key bitonic sort ->
// decode top-500 -> suppression matrix -> sequential keep-scan.
__global__ __launch_bounds__(1024) void topk_nms_kernel(
    const float* __restrict__ scores,
    const int* __restrict__ labels,
    const float* __restrict__ ptxywh,
    const float* __restrict__ grid_xy,
    const float* __restrict__ anchor_wh,
    const float* __restrict__ fsize,
    float* __restrict__ out, int B) {
    extern __shared__ unsigned char smem[];
    // phase 1 layout
    unsigned int* hist = (unsigned int*)smem;                     // [1024]  @0
    unsigned long long* cand = (unsigned long long*)(smem + 4096);// [2048]  @4096..20480
    unsigned int* cntp = (unsigned int*)(smem + 20480);
    unsigned int* Tp   = (unsigned int*)(smem + 20484);
    const int b = blockIdx.x;
    const int tid = threadIdx.x;
    const float* sb = scores + (size_t)b * A_N;

    // init
    hist[tid] = 0u;
    cand[tid] = 0ull;
    cand[tid + 1024] = 0ull;
    if (tid == 0) *cntp = 0u;
    __syncthreads();

    // histogram of top-12 float bits (all scores positive, < 1.0)
    for (int i = tid; i < A_N; i += 1024) {
        unsigned int u = __float_as_uint(sb[i]) >> 20;
        atomicAdd(&hist[u], 1u);
    }
    __syncthreads();

    // suffix scan (Hillis-Steele): hist[u] = count of items in buckets >= u
    for (int d = 1; d < NBUCK; d <<= 1) {
        unsigned int v = (tid + d < NBUCK) ? hist[tid + d] : 0u;
        __syncthreads();
        hist[tid] += v;
        __syncthreads();
    }
    // T = max u with cum[u] >= K_N  (cum[0] = A_N >= K_N always)
    if (hist[tid] >= K_N && (tid == NBUCK - 1 || hist[tid + 1] < K_N)) *Tp = (unsigned)tid;
    __syncthreads();
    const unsigned int T = *Tp;
    __syncthreads();

    // gather candidates (buckets >= T); expected ~800, cap CAND_N
    for (int i = tid; i < A_N; i += 1024) {
        unsigned int u = __float_as_uint(sb[i]);
        if ((u >> 20) >= T) {
            unsigned int slot = atomicAdd(cntp, 1u);
            if (slot < CAND_N)
                cand[slot] = ((unsigned long long)u << 32) |
                             (unsigned long long)(0xFFFFu - (unsigned)i);
        }
    }
    __syncthreads();

    // bitonic sort 2048 desc (1024 threads -> exactly one pair each)
    for (int sz = 2; sz <= CAND_N; sz <<= 1) {
        for (int j = sz >> 1; j > 0; j >>= 1) {
            int i = ((tid & ~(j - 1)) << 1) | (tid & (j - 1));
            int l = i | j;
            unsigned long long a = cand[i];
            unsigned long long c = cand[l];
            bool descBlk = ((i & sz) == 0);
            if (descBlk ? (a < c) : (a > c)) { cand[i] = c; cand[l] = a; }
            __syncthreads();
        }
    }

    unsigned long long myk = 0ull;
    if (tid < K_N) myk = cand[tid];
    __syncthreads();   // smem reusable now

    // phase 2 layout (bytes)
    float* bxL   = (float*)smem;                               // [500*4]
    float* areaL = (float*)(smem + 8000);                      // [500]
    int*   labL  = (int*)  (smem + 10000);                     // [500]
    float* valsL = (float*)(smem + 12000);                     // [500]
    unsigned long long* nzL   = (unsigned long long*)(smem + 14016); // [8]
    unsigned long long* keepL = (unsigned long long*)(smem + 14080); // [8]
    unsigned long long* supL  = (unsigned long long*)(smem + 14336); // [500*8]

    if (tid >= 512 && tid < 520) nzL[tid - 512] = 0ull;

    const size_t BK = (size_t)B * K_N;
    if (tid < K_N) {
        float scv = __uint_as_float((unsigned int)(myk >> 32));
        int idx = 0xFFFF - (int)(myk & 0xFFFFull);
        int lb = labels[(size_t)b * A_N + idx] + 1;
        const float* t4 = ptxywh + ((size_t)b * A_N + idx) * 4;
        float tx = t4[0], ty = t4[1], tw = t4[2], th = t4[3];
        float gx = grid_xy[idx * 2 + 0], gy = grid_xy[idx * 2 + 1];
        float aw = anchor_wh[idx * 2 + 0], ah = anchor_wh[idx * 2 + 1];
        float fs = fsize[idx];
        float cx = __fdiv_rn(__fadd_rn(sigmoid_ref(tx), gx), fs);
        float cy = __fdiv_rn(__fadd_rn(sigmoid_ref(ty), gy), fs);
        float wx = __fmul_rn(expf(tw), aw);
        float wy = __fmul_rn(expf(th), ah);
        float hx = __fmul_rn(0.5f, wx);
        float hy = __fmul_rn(0.5f, wy);
        float x0 = __fsub_rn(cx, hx), y0 = __fsub_rn(cy, hy);
        float x1 = __fadd_rn(cx, hx), y1 = __fadd_rn(cy, hy);
        x0 = fminf(fmaxf(x0, 0.0f), 1.0f);
        y0 = fminf(fmaxf(y0, 0.0f), 1.0f);
        x1 = fminf(fmaxf(x1, 0.0f), 1.0f);
        y1 = fminf(fmaxf(y1, 0.0f), 1.0f);
        float area = __fmul_rn(fmaxf(__fsub_rn(x1, x0), 0.0f),
                               fmaxf(__fsub_rn(y1, y0), 0.0f));
        bxL[tid * 4 + 0] = x0; bxL[tid * 4 + 1] = y0;
        bxL[tid * 4 + 2] = x1; bxL[tid * 4 + 3] = y1;
        areaL[tid] = area; labL[tid] = lb; valsL[tid] = scv;

        out[(size_t)b * K_N + tid] = (float)b;                         // ids_batch
        float* ob = out + BK + ((size_t)b * K_N + tid) * 4;            // boxes
        ob[0] = x0; ob[1] = y0; ob[2] = x1; ob[3] = y1;
        out[5 * BK + (size_t)b * K_N + tid] = (float)lb;               // labels
        out[6 * BK + (size_t)b * K_N + tid] = scv;                     // vals
    }
    __syncthreads();

    // suppression matrix: sup[i][j] for j>i, 500 rows x 8 u64 words
    for (int task = tid; task < K_N * 8; task += 1024) {
        int i = task >> 3;
        int w = task & 7;
        float li = bxL[i * 4 + 0], ti = bxL[i * 4 + 1];
        float ri = bxL[i * 4 + 2], bi = bxL[i * 4 + 3];
        float ai = areaL[i];
        int lbi = labL[i];
        unsigned long long bits = 0ull;
        int j0 = w * 64;
        int jend = j0 + 64; if (jend > K_N) jend = K_N;
        int jst = j0 > i + 1 ? j0 : i + 1;
        for (int j = jst; j < jend; ++j) {
            if (labL[j] == lbi) {
                float lj = bxL[j * 4 + 0], tj = bxL[j * 4 + 1];
                float rj = bxL[j * 4 + 2], bj = bxL[j * 4 + 3];
                float ltx = fmaxf(li, lj), lty = fmaxf(ti, tj);
                float rbx = fminf(ri, rj), rby = fminf(bi, bj);
                float iw = fmaxf(__fsub_rn(rbx, ltx), 0.0f);
                float ih = fmaxf(__fsub_rn(rby, lty), 0.0f);
                float inter = __fmul_rn(iw, ih);
                float den = __fadd_rn(__fsub_rn(__fadd_rn(ai, areaL[j]), inter), 1e-9f);
                float iou = __fdiv_rn(inter, den);
                if (iou > NMS_THRF) bits |= (1ull << (j - j0));
            }
        }
        supL[i * 8 + w] = bits;
        if (bits) atomicOr(&nzL[i >> 6], 1ull << (i & 63));
    }
    __syncthreads();

    // sequential keep-scan, wave 0, register-resident suppressed bitmask
    if (tid < 64) {
        const int lane = tid;
        unsigned long long supp = 0ull, keepm = 0ull;
        unsigned long long nzreg = (lane < 8) ? nzL[lane] : 0ull;
        #pragma unroll
        for (int t = 0; t < 8; ++t) {
            const int i0 = t * 64;
            int myi = i0 + lane;
            bool v = (myi < K_N) ? (valsL[myi] > CONF_THRF) : false;
            unsigned long long vword = __ballot(v);
            unsigned long long nzword = shfl_u64(nzreg, t);
            const int imax = (K_N - i0 < 64) ? (K_N - i0) : 64;
            for (int i2 = 0; i2 < imax; ++i2) {
                unsigned long long sw = shfl_u64(supp, t);
                bool keep_i = ((vword >> i2) & 1ull) && !((sw >> i2) & 1ull);
                if (keep_i) {
                    if (lane == t) keepm |= (1ull << i2);
                    if ((nzword >> i2) & 1ull) {
                        if (lane < 8) supp |= supL[(i0 + i2) * 8 + lane];
                    }
                }
            }
        }
        if (lane < 8) keepL[lane] = keepm;
    }
    __syncthreads();

    if (tid < K_N) {
        unsigned long long kw = keepL[tid >> 6];
        out[7 * BK + (size_t)b * K_N + tid] = (float)((kw >> (tid & 63)) & 1ull);
    }
}

extern "C" void kernel_launch(void* const* d_in, const int* in_sizes, int n_in,
                              void* d_out, int out_size, void* d_ws, size_t ws_size,
                              hipStream_t stream) {
    const float* pconf     = (const float*)d_in[0];
    const float* pcls      = (const float*)d_in[1];
    const float* ptxywh    = (const float*)d_in[2];
    const float* grid_xy   = (const float*)d_in[3];
    const float* anchor_wh = (const float*)d_in[4];
    const float* fsize     = (const float*)d_in[5];
    int total = in_sizes[0];          // B*A
    int B = total / A_N;
    if (B <= 0) return;

    float* scores = (float*)d_ws;
    int*   labls  = (int*)((char*)d_ws + (size_t)total * sizeof(float));
    float* out    = (float*)d_out;

    hipLaunchKernelGGL(score_kernel, dim3(B * SC_TILES), dim3(256), 0, stream,
                       pconf, pcls, scores, labls);
    hipLaunchKernelGGL(topk_nms_kernel, dim3(B), dim3(1024), 46592, stream,
                       scores, labls, ptxywh, grid_xy, anchor_wh, fsize, out, B);
}